// Round 1
// baseline (400.084 us; speedup 1.0000x reference)
//
#include <hip/hip_runtime.h>

#define NA    3
#define CP5   85
#define NC    80
#define NB    64
#define NG    52
#define GG    (NG * NG)        // 2704
#define NCELL (NB * GG)        // 173056
#define PLANE GG

// ws accumulators: [0]=coord_sum [1]=obj_sum [2]=cls_sum [3]=noobj_sum [4]=n_obj
__global__ __launch_bounds__(256) void yolo_main(const float* __restrict__ pred,
                                                 const float* __restrict__ targ,
                                                 float* __restrict__ acc) {
    int n = blockIdx.x * blockDim.x + threadIdx.x;
    float s_coord = 0.f, s_obj = 0.f, s_cls = 0.f, s_noobj = 0.f, cnt = 0.f;

    if (n < NCELL) {
        int b   = n / GG;
        int g   = n - b * GG;
        int row = g / NG;
        int col = g - row * NG;

        const float* pb = pred + (size_t)b * (NA * CP5) * PLANE + g;
        const float* tb = targ + (size_t)b * 6 * PLANE + g;

        float tobj = tb[4 * PLANE];
        // conf channels: needed for every cell (noobj term) — coalesced plane reads
        float c0 = pb[(0 * CP5 + 4) * PLANE];
        float c1 = pb[(1 * CP5 + 4) * PLANE];
        float c2 = pb[(2 * CP5 + 4) * PLANE];

        if (tobj == 1.0f) {
            cnt = 1.0f;
            const float cell = 1.0f / 52.0f;
            float tx = tb[0], ty = tb[PLANE], tw = tb[2 * PLANE], th = tb[3 * PLANE];
            int   tcls = (int)tb[5 * PLANE];

            float bx1 = tx - tw * 0.5f, by1 = ty - th * 0.5f;
            float bx2 = tx + tw * 0.5f, by2 = ty + th * 0.5f;
            float area_b = (bx2 - bx1) * (by2 - by1);

            float px[NA], py[NA], pw[NA], ph[NA], pc[NA];
            pc[0] = c0; pc[1] = c1; pc[2] = c2;
            float bestiou = -1e30f;
            int   best    = 0;
            #pragma unroll
            for (int a = 0; a < NA; ++a) {
                px[a] = pb[(a * CP5 + 0) * PLANE] + (float)col * cell;
                py[a] = pb[(a * CP5 + 1) * PLANE] + (float)row * cell;
                pw[a] = pb[(a * CP5 + 2) * PLANE];
                ph[a] = pb[(a * CP5 + 3) * PLANE];
                float ax1 = px[a] - pw[a] * 0.5f, ay1 = py[a] - ph[a] * 0.5f;
                float ax2 = px[a] + pw[a] * 0.5f, ay2 = py[a] + ph[a] * 0.5f;
                float iw = fminf(ax2, bx2) - fmaxf(ax1, bx1); iw = fmaxf(iw, 0.f);
                float ih = fminf(ay2, by2) - fmaxf(ay1, by1); ih = fmaxf(ih, 0.f);
                float inter  = iw * ih;
                float area_a = (ax2 - ax1) * (ay2 - ay1);
                float iou    = inter / (area_a + area_b - inter);
                if (iou > bestiou) { bestiou = iou; best = a; }  // strict > = first-occurrence argmax
            }

            float dx = px[best] - tx, dy = py[best] - ty;
            float dw = sqrtf(pw[best]) - sqrtf(tw);
            float dh = sqrtf(ph[best]) - sqrtf(th);
            s_coord = dx * dx + dy * dy + dw * dw + dh * dh;

            s_obj = -logf(pc[best]);

            // class cross-entropy: two passes over the 80 strided channels
            // (pass 2 re-reads from L1/L2 — HBM traffic counted once)
            const float* cls = pb + (best * CP5 + 5) * PLANE;
            float m = -1e30f;
            for (int c = 0; c < NC; ++c) m = fmaxf(m, cls[c * PLANE]);
            float s = 0.f;
            for (int c = 0; c < NC; ++c) s += expf(cls[c * PLANE] - m);
            float x_cls = cls[tcls * PLANE];
            s_cls = logf(s) - (x_cls - m);
        } else {
            s_noobj = -(logf(1.f - c0) + logf(1.f - c1) + logf(1.f - c2));
        }
    }

    // wave(64)-level reduction, then one atomicAdd per wave per accumulator
    #pragma unroll
    for (int o = 32; o > 0; o >>= 1) {
        s_coord += __shfl_down(s_coord, o);
        s_obj   += __shfl_down(s_obj, o);
        s_cls   += __shfl_down(s_cls, o);
        s_noobj += __shfl_down(s_noobj, o);
        cnt     += __shfl_down(cnt, o);
    }
    if ((threadIdx.x & 63) == 0) {
        atomicAdd(&acc[0], s_coord);
        atomicAdd(&acc[1], s_obj);
        atomicAdd(&acc[2], s_cls);
        atomicAdd(&acc[3], s_noobj);
        atomicAdd(&acc[4], cnt);
    }
}

__global__ void yolo_final(const float* __restrict__ acc, float* __restrict__ out) {
    float n_obj   = acc[4];
    float n_noobj = (float)NCELL - n_obj;
    float loss = acc[0] / (2.f * n_obj)       // coord (xy + sqrt-wh)
               + acc[1] / n_obj               // objectness
               + acc[2] / n_obj               // class CE
               + acc[3] / (n_noobj * 3.f);    // no-obj over all anchors
    out[0] = loss;
}

extern "C" void kernel_launch(void* const* d_in, const int* in_sizes, int n_in,
                              void* d_out, int out_size, void* d_ws, size_t ws_size,
                              hipStream_t stream) {
    const float* pred = (const float*)d_in[0];
    const float* targ = (const float*)d_in[1];
    float* out = (float*)d_out;
    float* acc = (float*)d_ws;

    hipMemsetAsync(acc, 0, 8 * sizeof(float), stream);  // ws is re-poisoned 0xAA each call
    yolo_main<<<dim3(NCELL / 256), dim3(256), 0, stream>>>(pred, targ, acc);
    yolo_final<<<1, 1, 0, stream>>>(acc, out);
}